// Round 3
// baseline (234.534 us; speedup 1.0000x reference)
//
#include <hip/hip_runtime.h>

#define NSTEPS 64

typedef __attribute__((ext_vector_type(16))) float float16_;   // 32x32 MFMA C/D
typedef __attribute__((ext_vector_type(2))) __fp16 half2_;     // packed f16
typedef __attribute__((ext_vector_type(8))) __fp16 half8_;     // f16 MFMA A/B operand

__device__ __forceinline__ half2_ relu_pk_f16(float a, float b) {
    half2_ h = __builtin_amdgcn_cvt_pkrtz(a, b);               // v_cvt_pkrtz_f16_f32
    return __builtin_elementwise_max(h, (half2_)(__fp16)0);    // v_pk_max_f16
}

// R13 layout (HW-verified; 32x32x16 f16 MFMA):
//   A[m][k]: m=lane&31, k=(lane>>5)*8+j
//   B[k][n]: n=lane&31, k=(lane>>5)*8+j
//   C/D[r][c]: c=lane&31, r=(reg&3)+8*(reg>>2)+4*(lane>>5)
//
// R16: all three layers on MFMA via the pi/nu permutations (see notes in
// fragment builders below). R17 (this round): TWO independent row-groups
// per wave (64 rows/wave). Weight/bias fragments are shared between the
// chains; only transient state duplicates. Two independent dependency
// chains per wave let the SIMD interleave MFMA issue of chain B into
// chain A's latency shadow — R2 counters showed we pay ~390 cyc/stage of
// pure chain latency vs ~130 cyc of issue.
__global__ __launch_bounds__(256, 3)
void ode_rk4_mfma(const float* __restrict__ x,
                  const float* __restrict__ samples,
                  const float* __restrict__ w1, const float* __restrict__ b1,
                  const float* __restrict__ w2, const float* __restrict__ b2,
                  const float* __restrict__ w3, const float* __restrict__ b3,
                  const float* __restrict__ w_out, const float* __restrict__ b_out,
                  float* __restrict__ out, int B)
{
    const int lane  = threadIdx.x & 63;
    const int w     = threadIdx.x >> 6;
    const int col32 = lane & 31;              // this lane's sample row (mod 32)
    const int half  = lane >> 5;              // 0..1

    const int rowBase = (blockIdx.x * 4 + w) * 64;
    const int rowA = rowBase + col32;          // chain-A row
    const int rowB = rowBase + 32 + col32;     // chain-B row

    // pi permutation: swap hidden-unit 4-blocks 1<->2 and 5<->6
    auto pi = [](int m) -> int {
        int bb = (m >> 2) & 3;
        return m + ((bb == 1) ? 4 : (bb == 2) ? -4 : 0);
    };

    // ---- persistent MFMA operands (built once; SHARED by both chains) ----
    // Layer1 A-frag: A1[m][k] = w1[k][pi(m)], k=0..2; zero elsewhere.
    union { half2_ h2[4]; half8_ h8; } A1;
    {
        int pm = pi(col32);
        if (half == 0) {
            A1.h2[0] = (half2_){(__fp16)w1[0 * 32 + pm], (__fp16)w1[1 * 32 + pm]};
            A1.h2[1] = (half2_){(__fp16)w1[2 * 32 + pm], (__fp16)0.0f};
        } else {
            A1.h2[0] = (half2_)(__fp16)0.0f;
            A1.h2[1] = (half2_)(__fp16)0.0f;
        }
        A1.h2[2] = (half2_)(__fp16)0.0f;
        A1.h2[3] = (half2_)(__fp16)0.0f;
    }
    // Layer1 bias C-frag: C1[r][c] = b1[pi(r)], r = (reg&3)+8*(reg>>2)+4*half
    float16_ C1;
#pragma unroll
    for (int r = 0; r < 16; ++r)
        C1[r] = b1[pi((r & 3) + 8 * (r >> 2) + 4 * half)];

    // W2^T A-frags: A2[m=j2][k=i1] = w2[i1*32 + j2]
    union { half2_ h2[4]; half8_ h8; } W2T1, W2T2;
#pragma unroll
    for (int pp = 0; pp < 4; ++pp) {
        int i1 = half * 8 + 2 * pp;
        W2T1.h2[pp] = (half2_){(__fp16)w2[i1 * 32 + col32], (__fp16)w2[(i1 + 1) * 32 + col32]};
        W2T2.h2[pp] = (half2_){(__fp16)w2[(i1 + 16) * 32 + col32], (__fp16)w2[(i1 + 17) * 32 + col32]};
    }
    // layer2 bias C-frag: Cb[r] = b2[j2(r)]
    float16_ Cb;
#pragma unroll
    for (int r = 0; r < 16; ++r)
        Cb[r] = b2[(r & 3) + 8 * (r >> 2) + 4 * half];

    // Layer3 A-frags: A3[m][k] = w3[nu(k)][m] for m<3 else 0;
    // nu(16t+8h+j) = 16t + 4h + (j&3) + 8*(j>>2)
    union { half2_ h2[4]; half8_ h8; } A31, A32;
#pragma unroll
    for (int pp = 0; pp < 4; ++pp) {
        int j0 = 2 * pp;
        int nu0 = 4 * half + (j0 & 3) + 8 * (j0 >> 2);
        if (col32 < 3) {
            A31.h2[pp] = (half2_){(__fp16)w3[nu0 * 3 + col32], (__fp16)w3[(nu0 + 1) * 3 + col32]};
            A32.h2[pp] = (half2_){(__fp16)w3[(nu0 + 16) * 3 + col32], (__fp16)w3[(nu0 + 17) * 3 + col32]};
        } else {
            A31.h2[pp] = (half2_)(__fp16)0.0f;
            A32.h2[pp] = (half2_)(__fp16)0.0f;
        }
    }
    // Layer3 bias C-frag: rows 0..2 (half=0, regs 0..2) get b3; rest 0.
    float16_ Cb3;
#pragma unroll
    for (int r = 0; r < 16; ++r)
        Cb3[r] = (half == 0 && r < 3) ? b3[r] : 0.0f;

    // ---- scalars ----
    const float maxT = samples[7];
    const float dt   = maxT / 64.0f;
    const float dt2  = 0.5f * dt;
    const float dt6  = dt / 6.0f;

    int sidx[8];
    unsigned long long smask = 0ull;
#pragma unroll
    for (int j = 0; j < 8; ++j) {
        int id = (int)rintf(samples[j] / dt) - 1;   // jnp.round = RNE
        id = id < 0 ? 0 : (id > NSTEPS - 1 ? NSTEPS - 1 : id);
        id = __builtin_amdgcn_readfirstlane(id);    // wave-uniform -> SGPR
        sidx[j] = id;
        smask |= 1ull << id;
    }
    const float wo0 = w_out[0], wo1 = w_out[1], wo2 = w_out[2];
    const float bo  = b_out[0];

    float ya0 = x[(size_t)rowA * 3 + 0];
    float ya1 = x[(size_t)rowA * 3 + 1];
    float ya2 = x[(size_t)rowA * 3 + 2];
    float yb0 = x[(size_t)rowB * 3 + 0];
    float yb1 = x[(size_t)rowB * 3 + 1];
    float yb2 = x[(size_t)rowB * 3 + 2];

#pragma unroll 1
    for (int s = 0; s < NSTEPS; ++s) {
        float accA0 = 0.f, accA1 = 0.f, accA2 = 0.f;
        float accB0 = 0.f, accB1 = 0.f, accB2 = 0.f;
        float aA0 = ya0, aA1 = ya1, aA2 = ya2;
        float aB0 = yb0, aB1 = yb1, aB2 = yb2;

#pragma unroll
        for (int st = 0; st < 4; ++st) {
            // ---- layer1 via MFMA, both chains (independent) ----
            half2_ aA01 = __builtin_amdgcn_cvt_pkrtz(aA0, aA1);
            half2_ aA2o = __builtin_amdgcn_cvt_pkrtz(aA2, 1.0f);
            half2_ aB01 = __builtin_amdgcn_cvt_pkrtz(aB0, aB1);
            half2_ aB2o = __builtin_amdgcn_cvt_pkrtz(aB2, 1.0f);
            union { half2_ h2[4]; half8_ h8; } LA, LB;
            LA.h2[0] = aA01; LA.h2[1] = aA2o; LA.h2[2] = aA01; LA.h2[3] = aA2o;
            LB.h2[0] = aB01; LB.h2[1] = aB2o; LB.h2[2] = aB01; LB.h2[3] = aB2o;

            float16_ D1A = __builtin_amdgcn_mfma_f32_32x32x16_f16(A1.h8, LA.h8, C1, 0, 0, 0);
            float16_ D1B = __builtin_amdgcn_mfma_f32_32x32x16_f16(A1.h8, LB.h8, C1, 0, 0, 0);

            // ---- relu-pack -> layer2 B-frags ----
            union { half2_ h2[4]; half8_ h8; } B1A, B2A, B1B, B2B;
#pragma unroll
            for (int pp = 0; pp < 4; ++pp) {
                B1A.h2[pp] = relu_pk_f16(D1A[2 * pp], D1A[2 * pp + 1]);
                B2A.h2[pp] = relu_pk_f16(D1A[8 + 2 * pp], D1A[8 + 2 * pp + 1]);
                B1B.h2[pp] = relu_pk_f16(D1B[2 * pp], D1B[2 * pp + 1]);
                B2B.h2[pp] = relu_pk_f16(D1B[8 + 2 * pp], D1B[8 + 2 * pp + 1]);
            }

            // ---- layer2: two chained MFMAs per chain (K=32) ----
            float16_ D2A = __builtin_amdgcn_mfma_f32_32x32x16_f16(W2T1.h8, B1A.h8,
                           __builtin_amdgcn_mfma_f32_32x32x16_f16(W2T2.h8, B2A.h8, Cb, 0, 0, 0), 0, 0, 0);
            float16_ D2B = __builtin_amdgcn_mfma_f32_32x32x16_f16(W2T1.h8, B1B.h8,
                           __builtin_amdgcn_mfma_f32_32x32x16_f16(W2T2.h8, B2B.h8, Cb, 0, 0, 0), 0, 0, 0);

            // ---- relu-pack -> layer3 B-frags ----
            union { half2_ h2[4]; half8_ h8; } H1A, H2A, H1B, H2B;
#pragma unroll
            for (int pp = 0; pp < 4; ++pp) {
                H1A.h2[pp] = relu_pk_f16(D2A[2 * pp], D2A[2 * pp + 1]);
                H2A.h2[pp] = relu_pk_f16(D2A[8 + 2 * pp], D2A[8 + 2 * pp + 1]);
                H1B.h2[pp] = relu_pk_f16(D2B[2 * pp], D2B[2 * pp + 1]);
                H2B.h2[pp] = relu_pk_f16(D2B[8 + 2 * pp], D2B[8 + 2 * pp + 1]);
            }

            // ---- layer3: two chained MFMAs per chain ----
            float16_ D3A = __builtin_amdgcn_mfma_f32_32x32x16_f16(A32.h8, H2A.h8,
                           __builtin_amdgcn_mfma_f32_32x32x16_f16(A31.h8, H1A.h8, Cb3, 0, 0, 0), 0, 0, 0);
            float16_ D3B = __builtin_amdgcn_mfma_f32_32x32x16_f16(A32.h8, H2B.h8,
                           __builtin_amdgcn_mfma_f32_32x32x16_f16(A31.h8, H1B.h8, Cb3, 0, 0, 0), 0, 0, 0);

            // partner half holds zeros -> add-after-swap needs no select
            float kA0 = D3A[0] + __shfl_xor(D3A[0], 32);
            float kA1 = D3A[1] + __shfl_xor(D3A[1], 32);
            float kA2 = D3A[2] + __shfl_xor(D3A[2], 32);
            float kB0 = D3B[0] + __shfl_xor(D3B[0], 32);
            float kB1 = D3B[1] + __shfl_xor(D3B[1], 32);
            float kB2 = D3B[2] + __shfl_xor(D3B[2], 32);

            const float ca = (st == 1 || st == 2) ? 2.0f : 1.0f;
            accA0 = fmaf(ca, kA0, accA0); accA1 = fmaf(ca, kA1, accA1); accA2 = fmaf(ca, kA2, accA2);
            accB0 = fmaf(ca, kB0, accB0); accB1 = fmaf(ca, kB1, accB1); accB2 = fmaf(ca, kB2, accB2);
            const float ci = (st == 2) ? dt : dt2;
            aA0 = fmaf(ci, kA0, ya0); aA1 = fmaf(ci, kA1, ya1); aA2 = fmaf(ci, kA2, ya2);
            aB0 = fmaf(ci, kB0, yb0); aB1 = fmaf(ci, kB1, yb1); aB2 = fmaf(ci, kB2, yb2);
        }
        ya0 = fmaf(dt6, accA0, ya0); ya1 = fmaf(dt6, accA1, ya1); ya2 = fmaf(dt6, accA2, ya2);
        yb0 = fmaf(dt6, accB0, yb0); yb1 = fmaf(dt6, accB1, yb1); yb2 = fmaf(dt6, accB2, yb2);

        // wave-uniform SALU fast path: most steps store nothing
        if ((smask >> s) & 1ull) {
            if (half == 0) {
#pragma unroll
                for (int j = 0; j < 8; ++j) {
                    if (sidx[j] == s) {
                        out[(size_t)j * B + rowA] = fmaf(ya2, wo2, fmaf(ya1, wo1, fmaf(ya0, wo0, bo)));
                        out[(size_t)j * B + rowB] = fmaf(yb2, wo2, fmaf(yb1, wo1, fmaf(yb0, wo0, bo)));
                    }
                }
            }
        }
    }
}

extern "C" void kernel_launch(void* const* d_in, const int* in_sizes, int n_in,
                              void* d_out, int out_size, void* d_ws, size_t ws_size,
                              hipStream_t stream) {
    const float* x       = (const float*)d_in[0];
    const float* samples = (const float*)d_in[1];
    const float* w1      = (const float*)d_in[2];
    const float* b1      = (const float*)d_in[3];
    const float* w2      = (const float*)d_in[4];
    const float* b2      = (const float*)d_in[5];
    const float* w3      = (const float*)d_in[6];
    const float* b3      = (const float*)d_in[7];
    const float* w_out   = (const float*)d_in[8];
    const float* b_out   = (const float*)d_in[9];
    float* out = (float*)d_out;

    const int B = in_sizes[0] / 3;           // 131072
    const int rowsPerBlock = 256;            // 4 waves x 64 rows (2 chains each)
    const int grid = (B + rowsPerBlock - 1) / rowsPerBlock;
    ode_rk4_mfma<<<grid, 256, 0, stream>>>(
        x, samples, w1, b1, w2, b2, w3, b3, w_out, b_out, out, B);
}

// Round 4
// 213.038 us; speedup vs baseline: 1.1009x; 1.1009x over previous
//
#include <hip/hip_runtime.h>

#define NSTEPS 64

typedef __attribute__((ext_vector_type(16))) float float16_;   // 32x32 MFMA C/D
typedef __attribute__((ext_vector_type(2))) __fp16 half2_;     // packed f16
typedef __attribute__((ext_vector_type(8))) __fp16 half8_;     // f16 MFMA A/B operand

__device__ __forceinline__ half2_ relu_pk_f16(float a, float b) {
    half2_ h = __builtin_amdgcn_cvt_pkrtz(a, b);               // v_cvt_pkrtz_f16_f32
    return __builtin_elementwise_max(h, (half2_)(__fp16)0);    // v_pk_max_f16
}

// R13 layout (HW-verified; 32x32x16 f16 MFMA):
//   A[m][k]: m=lane&31, k=(lane>>5)*8+j
//   B[k][n]: n=lane&31, k=(lane>>5)*8+j
//   C/D[r][c]: c=lane&31, r=(reg&3)+8*(reg>>2)+4*(lane>>5)
//
// R16: all layers on MFMA via pi/nu permutations. R18 (this round):
// occupancy push. R3 showed VALUBusy+MfmaUtil ~ 100% = ALTERNATION (serial
// chain per wave) with only ~2 waves/SIMD resident — reg-capped by the
// persistent C-frags in the unified VGPR/AGPR file. Cuts:
//   - b1 folded into A1 k=3 (B already carries 1.0 there) -> C1 gone
//   - b3 added post-reduce (3 SALU-operand adds/stage)    -> Cb3 gone
//   - shared zero C-frag Zc for layer1 + layer3-inner (16 regs, was 32)
//   - shfl_xor(32) -> v_permlane32_swap_b32 (VALU pipe, no LDS round-trip;
//     t+u sum trick is symmetric so swap direction can't affect result)
// Single chain/wave again (R3's 2-chain halved the grid and lost TLP).
// (256,3) caps alloc at 170; at ~115 actual regs HW residency = 4 waves/SIMD.
__global__ __launch_bounds__(256, 3)
void ode_rk4_mfma(const float* __restrict__ x,
                  const float* __restrict__ samples,
                  const float* __restrict__ w1, const float* __restrict__ b1,
                  const float* __restrict__ w2, const float* __restrict__ b2,
                  const float* __restrict__ w3, const float* __restrict__ b3,
                  const float* __restrict__ w_out, const float* __restrict__ b_out,
                  float* __restrict__ out, int B)
{
    const int lane  = threadIdx.x & 63;
    const int w     = threadIdx.x >> 6;
    const int col32 = lane & 31;              // this lane's sample row (mod 32)
    const int half  = lane >> 5;              // 0..1

    const int rowBase = (blockIdx.x * 4 + w) * 32;
    const int row = rowBase + col32;

    // pi permutation: swap hidden-unit 4-blocks 1<->2 and 5<->6
    auto pi = [](int m) -> int {
        int bb = (m >> 2) & 3;
        return m + ((bb == 1) ? 4 : (bb == 2) ? -4 : 0);
    };

    // ---- persistent MFMA operands ----
    // Layer1 A-frag: A1[m][k] = w1[k][pi(m)] for k=0..2, A1[m][3] = b1[pi(m)]
    // (B row 3 carries constant 1.0 -> bias folded, C becomes zero)
    union { half2_ h2[4]; half8_ h8; } A1;
    {
        int pm = pi(col32);
        if (half == 0) {
            A1.h2[0] = (half2_){(__fp16)w1[0 * 32 + pm], (__fp16)w1[1 * 32 + pm]};
            A1.h2[1] = (half2_){(__fp16)w1[2 * 32 + pm], (__fp16)b1[pm]};
        } else {
            A1.h2[0] = (half2_)(__fp16)0.0f;
            A1.h2[1] = (half2_)(__fp16)0.0f;
        }
        A1.h2[2] = (half2_)(__fp16)0.0f;
        A1.h2[3] = (half2_)(__fp16)0.0f;
    }

    // W2^T A-frags: A2[m=j2][k=i1] = w2[i1*32 + j2]
    union { half2_ h2[4]; half8_ h8; } W2T1, W2T2;
#pragma unroll
    for (int pp = 0; pp < 4; ++pp) {
        int i1 = half * 8 + 2 * pp;
        W2T1.h2[pp] = (half2_){(__fp16)w2[i1 * 32 + col32], (__fp16)w2[(i1 + 1) * 32 + col32]};
        W2T2.h2[pp] = (half2_){(__fp16)w2[(i1 + 16) * 32 + col32], (__fp16)w2[(i1 + 17) * 32 + col32]};
    }
    // layer2 bias C-frag: Cb[r] = b2[j2(r)]
    float16_ Cb;
#pragma unroll
    for (int r = 0; r < 16; ++r)
        Cb[r] = b2[(r & 3) + 8 * (r >> 2) + 4 * half];

    // Layer3 A-frags: A3[m][k] = w3[nu(k)][m] for m<3 else 0;
    // nu(16t+8h+j) = 16t + 4h + (j&3) + 8*(j>>2)
    union { half2_ h2[4]; half8_ h8; } A31, A32;
#pragma unroll
    for (int pp = 0; pp < 4; ++pp) {
        int j0 = 2 * pp;
        int nu0 = 4 * half + (j0 & 3) + 8 * (j0 >> 2);
        if (col32 < 3) {
            A31.h2[pp] = (half2_){(__fp16)w3[nu0 * 3 + col32], (__fp16)w3[(nu0 + 1) * 3 + col32]};
            A32.h2[pp] = (half2_){(__fp16)w3[(nu0 + 16) * 3 + col32], (__fp16)w3[(nu0 + 17) * 3 + col32]};
        } else {
            A31.h2[pp] = (half2_)(__fp16)0.0f;
            A32.h2[pp] = (half2_)(__fp16)0.0f;
        }
    }

    // shared zero C-frag (layer1 + layer3-inner)
    float16_ Zc;
#pragma unroll
    for (int r = 0; r < 16; ++r) Zc[r] = 0.0f;

    // ---- scalars ----
    const float maxT = samples[7];
    const float dt   = maxT / 64.0f;
    const float dt2  = 0.5f * dt;
    const float dt6  = dt / 6.0f;

    int sidx[8];
    unsigned long long smask = 0ull;
#pragma unroll
    for (int j = 0; j < 8; ++j) {
        int id = (int)rintf(samples[j] / dt) - 1;   // jnp.round = RNE
        id = id < 0 ? 0 : (id > NSTEPS - 1 ? NSTEPS - 1 : id);
        id = __builtin_amdgcn_readfirstlane(id);    // wave-uniform -> SGPR
        sidx[j] = id;
        smask |= 1ull << id;
    }
    const float wo0 = w_out[0], wo1 = w_out[1], wo2 = w_out[2];
    const float bo  = b_out[0];
    const float b30 = b3[0], b31 = b3[1], b32 = b3[2];

    float y0 = x[(size_t)row * 3 + 0];
    float y1 = x[(size_t)row * 3 + 1];
    float y2 = x[(size_t)row * 3 + 2];

#pragma unroll 1
    for (int s = 0; s < NSTEPS; ++s) {
        float acc0 = 0.f, acc1 = 0.f, acc2 = 0.f;
        float a0 = y0, a1 = y1, a2 = y2;

#pragma unroll
        for (int st = 0; st < 4; ++st) {
            // ---- layer1 via MFMA; bias rides k=3 against the 1.0 in a2o ----
            half2_ a01 = __builtin_amdgcn_cvt_pkrtz(a0, a1);
            half2_ a2o = __builtin_amdgcn_cvt_pkrtz(a2, 1.0f);
            union { half2_ h2[4]; half8_ h8; } BL1;
            BL1.h2[0] = a01; BL1.h2[1] = a2o;
            BL1.h2[2] = a01; BL1.h2[3] = a2o;   // k>=8: A==0, don't-care

            float16_ D1 = __builtin_amdgcn_mfma_f32_32x32x16_f16(A1.h8, BL1.h8, Zc, 0, 0, 0);

            // ---- relu-pack -> layer2 B-frags (pi makes register order exact)
            union { half2_ h2[4]; half8_ h8; } B1, B2;
#pragma unroll
            for (int pp = 0; pp < 4; ++pp) {
                B1.h2[pp] = relu_pk_f16(D1[2 * pp], D1[2 * pp + 1]);
                B2.h2[pp] = relu_pk_f16(D1[8 + 2 * pp], D1[8 + 2 * pp + 1]);
            }

            // ---- layer2: two chained MFMAs (K=32) ----
            float16_ D2 = __builtin_amdgcn_mfma_f32_32x32x16_f16(W2T1.h8, B1.h8,
                          __builtin_amdgcn_mfma_f32_32x32x16_f16(W2T2.h8, B2.h8, Cb, 0, 0, 0), 0, 0, 0);

            // ---- relu-pack -> layer3 B-frags ----
            union { half2_ h2[4]; half8_ h8; } H1, H2;
#pragma unroll
            for (int pp = 0; pp < 4; ++pp) {
                H1.h2[pp] = relu_pk_f16(D2[2 * pp], D2[2 * pp + 1]);
                H2.h2[pp] = relu_pk_f16(D2[8 + 2 * pp], D2[8 + 2 * pp + 1]);
            }

            // ---- layer3: two chained MFMAs; rows 0..2 live, partner rows 0 ----
            float16_ D3 = __builtin_amdgcn_mfma_f32_32x32x16_f16(A32.h8, H2.h8,
                          __builtin_amdgcn_mfma_f32_32x32x16_f16(A31.h8, H1.h8, Zc, 0, 0, 0), 0, 0, 0);

            // cross-half reduce on the VALU pipe: v_permlane32_swap with a=b=q
            // gives t+u = q[l] + q[l^32] in every lane (direction-symmetric).
            float t0 = D3[0], u0 = D3[0];
            float t1 = D3[1], u1 = D3[1];
            float t2 = D3[2], u2 = D3[2];
            asm volatile("v_permlane32_swap_b32 %0, %1" : "+v"(t0), "+v"(u0));
            asm volatile("v_permlane32_swap_b32 %0, %1" : "+v"(t1), "+v"(u1));
            asm volatile("v_permlane32_swap_b32 %0, %1" : "+v"(t2), "+v"(u2));
            float k0 = t0 + u0 + b30;
            float k1 = t1 + u1 + b31;
            float k2 = t2 + u2 + b32;

            const float ca = (st == 1 || st == 2) ? 2.0f : 1.0f;
            acc0 = fmaf(ca, k0, acc0); acc1 = fmaf(ca, k1, acc1); acc2 = fmaf(ca, k2, acc2);
            const float ci = (st == 2) ? dt : dt2;
            a0 = fmaf(ci, k0, y0); a1 = fmaf(ci, k1, y1); a2 = fmaf(ci, k2, y2);
        }
        y0 = fmaf(dt6, acc0, y0); y1 = fmaf(dt6, acc1, y1); y2 = fmaf(dt6, acc2, y2);

        // wave-uniform SALU fast path: most steps store nothing
        if ((smask >> s) & 1ull) {
            if (half == 0) {
#pragma unroll
                for (int j = 0; j < 8; ++j) {
                    if (sidx[j] == s) {
                        out[(size_t)j * B + row] = fmaf(y2, wo2, fmaf(y1, wo1, fmaf(y0, wo0, bo)));
                    }
                }
            }
        }
    }
}

extern "C" void kernel_launch(void* const* d_in, const int* in_sizes, int n_in,
                              void* d_out, int out_size, void* d_ws, size_t ws_size,
                              hipStream_t stream) {
    const float* x       = (const float*)d_in[0];
    const float* samples = (const float*)d_in[1];
    const float* w1      = (const float*)d_in[2];
    const float* b1      = (const float*)d_in[3];
    const float* w2      = (const float*)d_in[4];
    const float* b2      = (const float*)d_in[5];
    const float* w3      = (const float*)d_in[6];
    const float* b3      = (const float*)d_in[7];
    const float* w_out   = (const float*)d_in[8];
    const float* b_out   = (const float*)d_in[9];
    float* out = (float*)d_out;

    const int B = in_sizes[0] / 3;           // 131072
    const int rowsPerBlock = 128;            // 4 waves x 32 rows (1 chain each)
    const int grid = (B + rowsPerBlock - 1) / rowsPerBlock;
    ode_rk4_mfma<<<grid, 256, 0, stream>>>(
        x, samples, w1, b1, w2, b2, w3, b3, w_out, b_out, out, B);
}